// Round 2
// baseline (1545.974 us; speedup 1.0000x reference)
//
#include <hip/hip_runtime.h>
#include <hip/hip_bf16.h>
#include <cstdint>
#include <cstddef>

typedef __bf16 bf16_t;
typedef bf16_t bf16x4 __attribute__((ext_vector_type(4)));
typedef bf16_t bf16x8 __attribute__((ext_vector_type(8)));
typedef float f32x4 __attribute__((ext_vector_type(4)));

static constexpr int NROWS = 16384;
static constexpr int CDIM  = 1024;

// ---------------- helpers ----------------

// Async global->LDS 16B copy. LDS dest must be WAVE-UNIFORM base; HW adds lane*16.
__device__ __forceinline__ void gload16(const bf16_t* g, bf16_t* l) {
  __builtin_amdgcn_global_load_lds((const __attribute__((address_space(1))) void*)g,
                                   (__attribute__((address_space(3))) void*)l, 16, 0, 0);
}

// Fragment load for v_mfma_f32_16x16x32_bf16 from LINEAR row-major LDS tile
// (row stride 64 bf16). Verified mapping: lane(l15,g) holds A[l15][ks+4g+{0..3}]
// and A[l15][ks+4g+16+{0..3}].
__device__ __forceinline__ bf16x8 ldsfragL(const bf16_t* lds, int row, int kelem) {
  const bf16_t* p = lds + row * 64 + kelem;
  union { bf16x4 h[2]; bf16x8 v; } u;
  u.h[0] = *(const bf16x4*)(p);
  u.h[1] = *(const bf16x4*)(p + 16);
  return u.v;
}

// Swizzled variant (16B-granule XOR), row stride in bytes — used by attn_t (reg-staged).
__device__ __forceinline__ bf16x8 ldsfrag(const bf16_t* lds, int row, int ldbytes, int kbyte) {
  const char* p = (const char*)lds + row * ldbytes;
  int sw = (row & 7) << 4;
  union { bf16x4 h[2]; bf16x8 v; } u;
  u.h[0] = *(const bf16x4*)(p + ((kbyte) ^ sw));
  u.h[1] = *(const bf16x4*)(p + ((kbyte + 32) ^ sw));
  return u.v;
}

__device__ __forceinline__ float phi_fn(float v) {           // elu + 1
  return v > 0.f ? v + 1.f : expf(v);
}
__device__ __forceinline__ float gelu_fn(float v) {          // exact gelu
  return 0.5f * v * (1.f + erff(v * 0.70710678118654752f));
}

// ---------------- elementwise / prep ----------------

__global__ void cast_x_kernel(const float* __restrict__ x, bf16_t* __restrict__ xb, long n) {
  long i = (long)blockIdx.x * blockDim.x + threadIdx.x;
  long stride = (long)gridDim.x * blockDim.x;
  for (long e = i * 8; e < n; e += stride * 8) {
    float4 a = *(const float4*)(x + e);
    float4 b = *(const float4*)(x + e + 4);
    bf16x8 o;
    o[0] = (bf16_t)a.x; o[1] = (bf16_t)a.y; o[2] = (bf16_t)a.z; o[3] = (bf16_t)a.w;
    o[4] = (bf16_t)b.x; o[5] = (bf16_t)b.y; o[6] = (bf16_t)b.z; o[7] = (bf16_t)b.w;
    *(bf16x8*)(xb + e) = o;
  }
}

// Transpose-cast weights to column-major bf16 (Bt[n][k]); modes 0-2 also apply
// the head-major column permutation perm(c) = (c%8)*128 + c/8.
__global__ void prep_w_kernel(const float* __restrict__ Wq, const float* __restrict__ Wkv,
                              const float* __restrict__ W1, const float* __restrict__ W2,
                              bf16_t* __restrict__ wqkv_bt, bf16_t* __restrict__ w1bt,
                              bf16_t* __restrict__ w2bt) {
  __shared__ float tile[64][65];
  int mode = blockIdx.z;
  const float* src; int ld; bf16_t* dst; int permute;
  if (mode == 0)      { src = Wq;          ld = 1024; dst = wqkv_bt;                       permute = 1; }
  else if (mode == 1) { src = Wkv;         ld = 2048; dst = wqkv_bt + (size_t)1024 * 1024; permute = 1; }
  else if (mode == 2) { src = Wkv + 1024;  ld = 2048; dst = wqkv_bt + (size_t)2048 * 1024; permute = 1; }
  else if (mode == 3) { src = W1;          ld = 1024; dst = w1bt;                          permute = 0; }
  else                { src = W2;          ld = 1024; dst = w2bt;                          permute = 0; }
  int r0 = blockIdx.x * 64, c0 = blockIdx.y * 64;
  int tid = threadIdx.x;
#pragma unroll
  for (int i = 0; i < 16; i++) {
    int idx = i * 256 + tid; int rr = idx >> 6, cc = idx & 63;
    tile[rr][cc] = src[(size_t)(r0 + rr) * ld + c0 + cc];
  }
  __syncthreads();
#pragma unroll
  for (int i = 0; i < 16; i++) {
    int idx = i * 256 + tid; int cc = idx >> 6, rr = idx & 63;
    int c = c0 + cc;
    int a = permute ? (((c & 7) << 7) | (c >> 3)) : c;
    dst[(size_t)a * 1024 + r0 + rr] = (bf16_t)tile[rr][cc];
  }
}

// ---------------- main GEMM:  out = A[M][K] @ Bt[N][K]^T ----------------
// m97 structure: global_load_lds width-16 staging, linear LDS, 2 barriers/K-step.
// MODE 0: QKV (N=3072): cols [0,1024) -> phi -> o0; [1024,2048) -> phi -> o1; [2048,3072) -> o2
// MODE 1: FFN1: gelu(acc + bias[col]) -> o0
// MODE 2: FFN2: acc + bias[col] -> o0

template<int MODE>
__global__ __launch_bounds__(256, 3)
void gemm_bt_kernel(const bf16_t* __restrict__ A, const bf16_t* __restrict__ Bt,
                    const float* __restrict__ bias,
                    bf16_t* __restrict__ o0, bf16_t* __restrict__ o1, bf16_t* __restrict__ o2,
                    int M, int N, int K)
{
  __shared__ bf16_t As[128 * 64];
  __shared__ bf16_t Bs[128 * 64];
  const int tid  = threadIdx.x;
  const int lane = tid & 63;
  const int wave = tid >> 6;
  const int wr = (wave >> 1) * 64, wc = (wave & 1) * 64;
  const int l15 = lane & 15, g = lane >> 4;
  const int row0 = blockIdx.x * 128, col0 = blockIdx.y * 128;
  const int cb = wave * 256;                 // this wave's 256-chunk slice of 1024
  f32x4 acc[4][4] = {};

  for (int kt = 0; kt < K; kt += 64) {
    __syncthreads();                         // prior iter's LDS reads done
#pragma unroll
    for (int it = 0; it < 4; ++it) {
      int ch = cb + it * 64 + lane;          // 16B chunk id; r = ch>>3, c16 = ch&7
      int r = ch >> 3, c16 = ch & 7;
      gload16(A  + (size_t)(row0 + r) * K + kt + c16 * 8, As + (size_t)(cb + it * 64) * 8);
      gload16(Bt + (size_t)(col0 + r) * K + kt + c16 * 8, Bs + (size_t)(cb + it * 64) * 8);
    }
    __syncthreads();                         // compiler drains vmcnt before barrier
#pragma unroll
    for (int ks = 0; ks < 64; ks += 32) {
      bf16x8 af[4], bfr[4];
#pragma unroll
      for (int i = 0; i < 4; i++) af[i]  = ldsfragL(As, wr + i * 16 + l15, ks + 4 * g);
#pragma unroll
      for (int i = 0; i < 4; i++) bfr[i] = ldsfragL(Bs, wc + i * 16 + l15, ks + 4 * g);
#pragma unroll
      for (int i = 0; i < 4; i++)
#pragma unroll
        for (int j = 0; j < 4; j++)
          acc[i][j] = __builtin_amdgcn_mfma_f32_16x16x32_bf16(af[i], bfr[j], acc[i][j], 0, 0, 0);
    }
  }

  // epilogue: D col = l&15, row = 4*(lane>>4) + reg
#pragma unroll
  for (int i = 0; i < 4; i++) {
    int rbase = row0 + wr + i * 16 + g * 4;
#pragma unroll
    for (int j = 0; j < 4; j++) {
      int col = col0 + wc + j * 16 + l15;
      f32x4 v = acc[i][j];
      if constexpr (MODE == 0) {
        int seg = col >> 10;
        int cl  = col & 1023;
        bf16_t* dst = (seg == 0) ? o0 : (seg == 1 ? o1 : o2);
#pragma unroll
        for (int rr = 0; rr < 4; rr++) {
          float val = v[rr];
          if (seg != 2) val = phi_fn(val);
          dst[(size_t)(rbase + rr) * 1024 + cl] = (bf16_t)val;
        }
      } else if constexpr (MODE == 1) {
        float bv = bias[col];
#pragma unroll
        for (int rr = 0; rr < 4; rr++)
          o0[(size_t)(rbase + rr) * 1024 + col] = (bf16_t)gelu_fn(v[rr] + bv);
      } else {
        float bv = bias[col];
#pragma unroll
        for (int rr = 0; rr < 4; rr++)
          o0[(size_t)(rbase + rr) * 1024 + col] = (bf16_t)(v[rr] + bv);
      }
    }
  }
}

// ---------------- kv_sum (split-K VALU outer product, f32 atomics) ----------------
// 512 blocks (64 n-chunks x 8 heads), chunk=256 rows, gload_lds staging.

__global__ __launch_bounds__(256, 4)
void kvsum_kernel(const bf16_t* __restrict__ phik, const bf16_t* __restrict__ vb,
                  float* __restrict__ Mf)
{
  __shared__ bf16_t kls[64 * 128];
  __shared__ bf16_t vls[64 * 128];
  const int h = blockIdx.y;
  const int n0 = blockIdx.x * 256;
  const int tid = threadIdx.x;
  const int lane = tid & 63, wave = tid >> 6;
  const int cb = wave * 256;
  const int ek0 = (tid >> 4) * 8, ev0 = (tid & 15) * 8;
  float acc[8][8] = {};

  for (int nt = 0; nt < 4; ++nt) {
    __syncthreads();
#pragma unroll
    for (int it = 0; it < 4; ++it) {
      int ch = cb + it * 64 + lane;          // 1024 chunks of 16B per matrix
      int r = ch >> 4, c16 = ch & 15;
      const size_t gsrc = (size_t)(n0 + nt * 64 + r) * 1024 + h * 128 + c16 * 8;
      gload16(phik + gsrc, kls + (size_t)(cb + it * 64) * 8);
      gload16(vb   + gsrc, vls + (size_t)(cb + it * 64) * 8);
    }
    __syncthreads();
#pragma unroll 2
    for (int n = 0; n < 64; n++) {
      bf16x8 a8 = *(const bf16x8*)(kls + n * 128 + ek0);
      bf16x8 b8 = *(const bf16x8*)(vls + n * 128 + ev0);
      float a[8], b[8];
#pragma unroll
      for (int i = 0; i < 8; i++) { a[i] = (float)a8[i]; b[i] = (float)b8[i]; }
#pragma unroll
      for (int i = 0; i < 8; i++)
#pragma unroll
        for (int j = 0; j < 8; j++) acc[i][j] += a[i] * b[j];
    }
  }
#pragma unroll
  for (int i = 0; i < 8; i++)
#pragma unroll
    for (int j = 0; j < 8; j++)
      atomicAdd(&Mf[(size_t)h * 16384 + (ek0 + i) * 128 + ev0 + j], acc[i][j]);
}

// z[col] = sum_n phik[n][col]  (memory-bound column sum; col is head-major = h*128+e)
__global__ void zsum_kernel(const bf16_t* __restrict__ phik, float* __restrict__ z) {
  int col = blockIdx.x * 256 + threadIdx.x;   // grid.x = 4
  int n0 = blockIdx.y * 256;                  // grid.y = 64
  float s = 0.f;
  for (int n = 0; n < 256; ++n) s += (float)phik[(size_t)(n0 + n) * 1024 + col];
  atomicAdd(&z[col], s);
}

// Mbt[h][e][d] = (bf16) Mf[h][d][e]
__global__ void castM_kernel(const float* __restrict__ Mf, bf16_t* __restrict__ Mbt) {
  int i = blockIdx.x * 256 + threadIdx.x;    // 8*128*128 total
  int h = i >> 14, rem = i & 16383, d = rem >> 7, e = rem & 127;
  Mbt[(size_t)h * 16384 + e * 128 + d] = (bf16_t)Mf[i];
}

// ---------------- attention num/den/t  (t = (phiq @ kvsum) / (phiq . z + eps)) ----------------

__global__ __launch_bounds__(256, 2)
void attn_t_kernel(const bf16_t* __restrict__ phiq, const bf16_t* __restrict__ Mbt,
                   const float* __restrict__ z, bf16_t* __restrict__ tout)
{
  __shared__ bf16_t As[64 * 128];   // phiq rows (this block's 64 rows, head h's 128 k-cols)
  __shared__ bf16_t Bs[128 * 128];  // Mbt[h] : [e][d]
  __shared__ float  zs[128];
  __shared__ float  dens[64];
  int h = blockIdx.y, row0 = blockIdx.x * 64;
  int tid = threadIdx.x, lane = tid & 63, wave = tid >> 6;
  int wr = (wave >> 1) * 32, wc = (wave & 1) * 64;
  int l15 = lane & 15, g = lane >> 4;

#pragma unroll
  for (int it = 0; it < 4; ++it) {          // A: 64x128 = 1024 chunks
    int ch = it * 256 + tid;
    int r = ch >> 4, c8 = ch & 15;
    int cs = c8 ^ (r & 7);
    *(bf16x8*)(As + r * 128 + cs * 8) = *(const bf16x8*)(phiq + (size_t)(row0 + r) * 1024 + h * 128 + c8 * 8);
  }
#pragma unroll
  for (int it = 0; it < 8; ++it) {          // B: 128x128 = 2048 chunks
    int ch = it * 256 + tid;
    int r = ch >> 4, c8 = ch & 15;
    int cs = c8 ^ (r & 7);
    *(bf16x8*)(Bs + r * 128 + cs * 8) = *(const bf16x8*)(Mbt + (size_t)h * 16384 + ch * 8);
  }
  if (tid < 128) zs[tid] = z[h * 128 + tid];
  __syncthreads();

  f32x4 acc[2][4] = {};
#pragma unroll
  for (int ks = 0; ks < 128; ks += 32) {
    bf16x8 af[2], bfr[4];
#pragma unroll
    for (int i = 0; i < 2; i++) af[i]  = ldsfrag(As, wr + i * 16 + l15, 256, ks * 2 + 8 * g);
#pragma unroll
    for (int j = 0; j < 4; j++) bfr[j] = ldsfrag(Bs, wc + j * 16 + l15, 256, ks * 2 + 8 * g);
#pragma unroll
    for (int i = 0; i < 2; i++)
#pragma unroll
      for (int j = 0; j < 4; j++)
        acc[i][j] = __builtin_amdgcn_mfma_f32_16x16x32_bf16(af[i], bfr[j], acc[i][j], 0, 0, 0);
  }

  if (tid < 64) {                            // den for this block's 64 rows (skewed, swizzle-aware)
    float s = 0.f;
    const char* p = (const char*)As + tid * 256;
    int sw = (tid & 7) << 4;
    for (int d0 = 0; d0 < 128; ++d0) {
      int d = (d0 + tid) & 127;
      bf16_t kv = *(const bf16_t*)(p + ((2 * d) ^ sw));
      s += (float)kv * zs[d];
    }
    dens[tid] = s;
  }
  __syncthreads();

#pragma unroll
  for (int i = 0; i < 2; i++) {
    int lr = wr + i * 16 + g * 4;
#pragma unroll
    for (int j = 0; j < 4; j++) {
      int col = h * 128 + wc + j * 16 + l15;
      f32x4 v = acc[i][j];
#pragma unroll
      for (int rr = 0; rr < 4; rr++) {
        float den = dens[lr + rr] + 1e-6f;
        tout[(size_t)(row0 + lr + rr) * 1024 + col] = (bf16_t)(v[rr] / den);
      }
    }
  }
}

// ---------------- LayerNorms ----------------

// y = LN(unpermute(t) + x) * g + b   (y bf16, natural layout)
__global__ __launch_bounds__(256, 2)
void ln1_kernel(const bf16_t* __restrict__ t, const float* __restrict__ x,
                const float* __restrict__ gma, const float* __restrict__ bta,
                bf16_t* __restrict__ y)
{
  __shared__ float s[1024];
  __shared__ float rsum[4], rsq[4];
  int n = blockIdx.x, tid = threadIdx.x;
#pragma unroll
  for (int k = 0; k < 4; k++) {
    int p = k * 256 + tid;
    float tv = (float)t[(size_t)n * 1024 + p];
    int c = ((p & 127) << 3) | (p >> 7);     // nat(p)
    s[c] = tv;
  }
  __syncthreads();
  float sum = 0.f, sq = 0.f, sv[4];
#pragma unroll
  for (int k = 0; k < 4; k++) {
    int c = k * 256 + tid;
    float v = s[c] + x[(size_t)n * 1024 + c];
    sv[k] = v; sum += v; sq += v * v;
  }
#pragma unroll
  for (int o = 32; o > 0; o >>= 1) { sum += __shfl_down(sum, o); sq += __shfl_down(sq, o); }
  if ((tid & 63) == 0) { rsum[tid >> 6] = sum; rsq[tid >> 6] = sq; }
  __syncthreads();
  sum = rsum[0] + rsum[1] + rsum[2] + rsum[3];
  sq  = rsq[0] + rsq[1] + rsq[2] + rsq[3];
  float mu = sum * (1.f / 1024.f);
  float var = sq * (1.f / 1024.f) - mu * mu;
  float rs = rsqrtf(var + 1e-5f);
#pragma unroll
  for (int k = 0; k < 4; k++) {
    int c = k * 256 + tid;
    y[(size_t)n * 1024 + c] = (bf16_t)((sv[k] - mu) * rs * gma[c] + bta[c]);
  }
}

// out = LN(f + y) * g + b   (f,y bf16 natural; out f32)
__global__ __launch_bounds__(256, 2)
void ln2_kernel(const bf16_t* __restrict__ f, const bf16_t* __restrict__ y,
                const float* __restrict__ gma, const float* __restrict__ bta,
                float* __restrict__ out)
{
  __shared__ float rsum[4], rsq[4];
  int n = blockIdx.x, tid = threadIdx.x;
  float sum = 0.f, sq = 0.f, sv[4];
#pragma unroll
  for (int k = 0; k < 4; k++) {
    int c = k * 256 + tid;
    float v = (float)f[(size_t)n * 1024 + c] + (float)y[(size_t)n * 1024 + c];
    sv[k] = v; sum += v; sq += v * v;
  }
#pragma unroll
  for (int o = 32; o > 0; o >>= 1) { sum += __shfl_down(sum, o); sq += __shfl_down(sq, o); }
  if ((tid & 63) == 0) { rsum[tid >> 6] = sum; rsq[tid >> 6] = sq; }
  __syncthreads();
  sum = rsum[0] + rsum[1] + rsum[2] + rsum[3];
  sq  = rsq[0] + rsq[1] + rsq[2] + rsq[3];
  float mu = sum * (1.f / 1024.f);
  float var = sq * (1.f / 1024.f) - mu * mu;
  float rs = rsqrtf(var + 1e-5f);
#pragma unroll
  for (int k = 0; k < 4; k++) {
    int c = k * 256 + tid;
    out[(size_t)n * 1024 + c] = (sv[k] - mu) * rs * gma[c] + bta[c];
  }
}

// ---------------- launcher ----------------

extern "C" void kernel_launch(void* const* d_in, const int* in_sizes, int n_in,
                              void* d_out, int out_size, void* d_ws, size_t ws_size,
                              hipStream_t stream)
{
  const float* x    = (const float*)d_in[0];
  const float* Wq   = (const float*)d_in[1];
  const float* Wkv  = (const float*)d_in[2];
  const float* g1   = (const float*)d_in[3];
  const float* bt1  = (const float*)d_in[4];
  const float* W1   = (const float*)d_in[5];
  const float* b1   = (const float*)d_in[6];
  const float* W2   = (const float*)d_in[7];
  const float* b2   = (const float*)d_in[8];
  const float* g2   = (const float*)d_in[9];
  const float* bt2  = (const float*)d_in[10];
  float* out = (float*)d_out;

  char* ws = (char*)d_ws;
  size_t off = 0;
  auto alloc = [&](size_t bytes) { void* p = ws + off; off += (bytes + 255) & ~(size_t)255; return p; };

  const size_t NC2 = (size_t)NROWS * CDIM * 2;          // 33.5 MB (bf16 [N][C])
  bf16_t* xb    = (bf16_t*)alloc(NC2);                  // xb, later reused as t
  bf16_t* wqkv  = (bf16_t*)alloc((size_t)3072 * 1024 * 2);
  bf16_t* w1bt  = (bf16_t*)alloc((size_t)1024 * 1024 * 2);
  bf16_t* w2bt  = (bf16_t*)alloc((size_t)1024 * 1024 * 2);
  bf16_t* phiq  = (bf16_t*)alloc(NC2);
  bf16_t* phik  = (bf16_t*)alloc(NC2);                  // later reused as h
  bf16_t* vbuf  = (bf16_t*)alloc(NC2);                  // later reused as f
  bf16_t* ybuf  = (bf16_t*)alloc(NC2);
  float*  Mf    = (float*)alloc(524288 + 4096);         // Mf[8][128][128] + z[1024]
  float*  zbuf  = Mf + 131072;
  bf16_t* Mbt   = (bf16_t*)alloc(262144);
  bf16_t* tbuf  = xb;                                   // alias (xb dead after QKV GEMM)
  bf16_t* hbuf  = phik;                                 // alias (phik dead after kvsum/zsum)
  bf16_t* fbuf  = vbuf;                                 // alias (v dead after kvsum)

  hipMemsetAsync(Mf, 0, 524288 + 4096, stream);

  cast_x_kernel<<<2048, 256, 0, stream>>>(x, xb, (long)NROWS * CDIM);
  prep_w_kernel<<<dim3(16, 16, 5), 256, 0, stream>>>(Wq, Wkv, W1, W2, wqkv, w1bt, w2bt);

  gemm_bt_kernel<0><<<dim3(128, 24), 256, 0, stream>>>(xb, wqkv, nullptr, phiq, phik, vbuf,
                                                       NROWS, 3072, 1024);
  kvsum_kernel<<<dim3(64, 8), 256, 0, stream>>>(phik, vbuf, Mf);
  zsum_kernel<<<dim3(4, 64), 256, 0, stream>>>(phik, zbuf);
  castM_kernel<<<512, 256, 0, stream>>>(Mf, Mbt);
  attn_t_kernel<<<dim3(256, 8), 256, 0, stream>>>(phiq, Mbt, zbuf, tbuf);
  ln1_kernel<<<NROWS, 256, 0, stream>>>(tbuf, x, g1, bt1, ybuf);

  gemm_bt_kernel<1><<<dim3(128, 8), 256, 0, stream>>>(ybuf, w1bt, b1, hbuf, nullptr, nullptr,
                                                      NROWS, 1024, 1024);
  gemm_bt_kernel<2><<<dim3(128, 8), 256, 0, stream>>>(hbuf, w2bt, b2, fbuf, nullptr, nullptr,
                                                      NROWS, 1024, 1024);
  ln2_kernel<<<NROWS, 256, 0, stream>>>(fbuf, ybuf, g2, bt2, out);
}

// Round 3
// 676.260 us; speedup vs baseline: 2.2861x; 2.2861x over previous
//
#include <hip/hip_runtime.h>
#include <hip/hip_bf16.h>
#include <cstdint>
#include <cstddef>

typedef __bf16 bf16_t;
typedef bf16_t bf16x4 __attribute__((ext_vector_type(4)));
typedef bf16_t bf16x8 __attribute__((ext_vector_type(8)));
typedef float f32x4 __attribute__((ext_vector_type(4)));

static constexpr int NROWS = 16384;
static constexpr int CDIM  = 1024;

// ---------------- helpers ----------------

// Async global->LDS 16B copy. LDS dest is WAVE-UNIFORM base; HW adds lane*16.
// Global src is PER-LANE -> swizzled LDS layouts are achieved by pre-swizzling
// the per-lane global address while keeping the LDS dest linear (rule #21).
__device__ __forceinline__ void gload16(const bf16_t* g, bf16_t* l) {
  __builtin_amdgcn_global_load_lds((const __attribute__((address_space(1))) void*)g,
                                   (__attribute__((address_space(3))) void*)l, 16, 0, 0);
}

// Fragment load for v_mfma_f32_16x16x32_bf16 from a row-major LDS tile whose
// 16B granules are XOR-swizzled: granule byte-address ^= (row&7)<<4.
// Lane(l15,g) holds A[row][ks+4g+{0..3}] and A[row][ks+4g+16+{0..3}].
__device__ __forceinline__ bf16x8 ldsfrag(const bf16_t* lds, int row, int ldbytes, int kbyte) {
  const char* p = (const char*)lds + row * ldbytes;
  int sw = (row & 7) << 4;
  union { bf16x4 h[2]; bf16x8 v; } u;
  u.h[0] = *(const bf16x4*)(p + ((kbyte) ^ sw));
  u.h[1] = *(const bf16x4*)(p + ((kbyte + 32) ^ sw));
  return u.v;
}

__device__ __forceinline__ float phi_fn(float v) {           // elu + 1
  return v > 0.f ? v + 1.f : expf(v);
}
__device__ __forceinline__ float gelu_fn(float v) {          // exact gelu
  return 0.5f * v * (1.f + erff(v * 0.70710678118654752f));
}

// ---------------- elementwise / prep ----------------

__global__ void cast_x_kernel(const float* __restrict__ x, bf16_t* __restrict__ xb, long n) {
  long i = (long)blockIdx.x * blockDim.x + threadIdx.x;
  long stride = (long)gridDim.x * blockDim.x;
  for (long e = i * 8; e < n; e += stride * 8) {
    float4 a = *(const float4*)(x + e);
    float4 b = *(const float4*)(x + e + 4);
    bf16x8 o;
    o[0] = (bf16_t)a.x; o[1] = (bf16_t)a.y; o[2] = (bf16_t)a.z; o[3] = (bf16_t)a.w;
    o[4] = (bf16_t)b.x; o[5] = (bf16_t)b.y; o[6] = (bf16_t)b.z; o[7] = (bf16_t)b.w;
    *(bf16x8*)(xb + e) = o;
  }
}

// Transpose-cast weights to column-major bf16 (Bt[n][k]); modes 0-2 also apply
// the head-major column permutation perm(c) = (c%8)*128 + c/8.
__global__ void prep_w_kernel(const float* __restrict__ Wq, const float* __restrict__ Wkv,
                              const float* __restrict__ W1, const float* __restrict__ W2,
                              bf16_t* __restrict__ wqkv_bt, bf16_t* __restrict__ w1bt,
                              bf16_t* __restrict__ w2bt) {
  __shared__ float tile[64][65];
  int mode = blockIdx.z;
  const float* src; int ld; bf16_t* dst; int permute;
  if (mode == 0)      { src = Wq;          ld = 1024; dst = wqkv_bt;                       permute = 1; }
  else if (mode == 1) { src = Wkv;         ld = 2048; dst = wqkv_bt + (size_t)1024 * 1024; permute = 1; }
  else if (mode == 2) { src = Wkv + 1024;  ld = 2048; dst = wqkv_bt + (size_t)2048 * 1024; permute = 1; }
  else if (mode == 3) { src = W1;          ld = 1024; dst = w1bt;                          permute = 0; }
  else                { src = W2;          ld = 1024; dst = w2bt;                          permute = 0; }
  int r0 = blockIdx.x * 64, c0 = blockIdx.y * 64;
  int tid = threadIdx.x;
#pragma unroll
  for (int i = 0; i < 16; i++) {
    int idx = i * 256 + tid; int rr = idx >> 6, cc = idx & 63;
    tile[rr][cc] = src[(size_t)(r0 + rr) * ld + c0 + cc];
  }
  __syncthreads();
#pragma unroll
  for (int i = 0; i < 16; i++) {
    int idx = i * 256 + tid; int cc = idx >> 6, rr = idx & 63;
    int c = c0 + cc;
    int a = permute ? (((c & 7) << 7) | (c >> 3)) : c;
    dst[(size_t)a * 1024 + r0 + rr] = (bf16_t)tile[rr][cc];
  }
}

// ---------------- main GEMM:  out = A[M][K] @ Bt[N][K]^T ----------------
// m97 staging (global_load_lds width-16) + m201-style swizzle: LDS dest linear,
// global source column pre-XOR'd (c16 ^= r&7), reads via swizzled ldsfrag.
// MODE 0: QKV (N=3072): cols [0,1024) -> phi -> o0; [1024,2048) -> phi -> o1; [2048,3072) -> o2
// MODE 1: FFN1: gelu(acc + bias[col]) -> o0
// MODE 2: FFN2: acc + bias[col] -> o0

template<int MODE>
__global__ __launch_bounds__(256, 3)
void gemm_bt_kernel(const bf16_t* __restrict__ A, const bf16_t* __restrict__ Bt,
                    const float* __restrict__ bias,
                    bf16_t* __restrict__ o0, bf16_t* __restrict__ o1, bf16_t* __restrict__ o2,
                    int M, int N, int K)
{
  __shared__ bf16_t As[128 * 64];
  __shared__ bf16_t Bs[128 * 64];
  const int tid  = threadIdx.x;
  const int lane = tid & 63;
  const int wave = tid >> 6;
  const int wr = (wave >> 1) * 64, wc = (wave & 1) * 64;
  const int l15 = lane & 15, g = lane >> 4;
  const int row0 = blockIdx.x * 128, col0 = blockIdx.y * 128;
  const int cb = wave * 256;                 // this wave's 256-chunk slice of 1024
  f32x4 acc[4][4] = {};

  for (int kt = 0; kt < K; kt += 64) {
    __syncthreads();                         // prior iter's LDS reads done
#pragma unroll
    for (int it = 0; it < 4; ++it) {
      int ch = cb + it * 64 + lane;          // LDS 16B-chunk id (linear dest)
      int r = ch >> 3;
      int csrc = (ch & 7) ^ (r & 7);         // inverse-swizzled source column
      gload16(A  + (size_t)(row0 + r) * K + kt + csrc * 8, As + (size_t)(cb + it * 64) * 8);
      gload16(Bt + (size_t)(col0 + r) * K + kt + csrc * 8, Bs + (size_t)(cb + it * 64) * 8);
    }
    __syncthreads();                         // compiler drains vmcnt before barrier
#pragma unroll
    for (int ks = 0; ks < 64; ks += 32) {
      bf16x8 af[4], bfr[4];
#pragma unroll
      for (int i = 0; i < 4; i++) af[i]  = ldsfrag(As, wr + i * 16 + l15, 128, ks * 2 + 8 * g);
#pragma unroll
      for (int i = 0; i < 4; i++) bfr[i] = ldsfrag(Bs, wc + i * 16 + l15, 128, ks * 2 + 8 * g);
#pragma unroll
      for (int i = 0; i < 4; i++)
#pragma unroll
        for (int j = 0; j < 4; j++)
          acc[i][j] = __builtin_amdgcn_mfma_f32_16x16x32_bf16(af[i], bfr[j], acc[i][j], 0, 0, 0);
    }
  }

  // epilogue: D col = l&15, row = 4*(lane>>4) + reg
#pragma unroll
  for (int i = 0; i < 4; i++) {
    int rbase = row0 + wr + i * 16 + g * 4;
#pragma unroll
    for (int j = 0; j < 4; j++) {
      int col = col0 + wc + j * 16 + l15;
      f32x4 v = acc[i][j];
      if constexpr (MODE == 0) {
        int seg = col >> 10;
        int cl  = col & 1023;
        bf16_t* dst = (seg == 0) ? o0 : (seg == 1 ? o1 : o2);
#pragma unroll
        for (int rr = 0; rr < 4; rr++) {
          float val = v[rr];
          if (seg != 2) val = phi_fn(val);
          dst[(size_t)(rbase + rr) * 1024 + cl] = (bf16_t)val;
        }
      } else if constexpr (MODE == 1) {
        float bv = bias[col];
#pragma unroll
        for (int rr = 0; rr < 4; rr++)
          o0[(size_t)(rbase + rr) * 1024 + col] = (bf16_t)gelu_fn(v[rr] + bv);
      } else {
        float bv = bias[col];
#pragma unroll
        for (int rr = 0; rr < 4; rr++)
          o0[(size_t)(rbase + rr) * 1024 + col] = (bf16_t)(v[rr] + bv);
      }
    }
  }
}

// ---------------- kv_sum (split-K VALU outer product, f32 atomics) ----------------
// 512 blocks (64 n-chunks x 8 heads), chunk=256 rows, gload_lds staging.

__global__ __launch_bounds__(256, 4)
void kvsum_kernel(const bf16_t* __restrict__ phik, const bf16_t* __restrict__ vb,
                  float* __restrict__ Mf)
{
  __shared__ bf16_t kls[64 * 128];
  __shared__ bf16_t vls[64 * 128];
  const int h = blockIdx.y;
  const int n0 = blockIdx.x * 256;
  const int tid = threadIdx.x;
  const int lane = tid & 63, wave = tid >> 6;
  const int cb = wave * 256;
  const int ek0 = (tid >> 4) * 8, ev0 = (tid & 15) * 8;
  float acc[8][8] = {};

  for (int nt = 0; nt < 4; ++nt) {
    __syncthreads();
#pragma unroll
    for (int it = 0; it < 4; ++it) {
      int ch = cb + it * 64 + lane;          // 1024 chunks of 16B per matrix
      int r = ch >> 4, c16 = ch & 15;
      const size_t gsrc = (size_t)(n0 + nt * 64 + r) * 1024 + h * 128 + c16 * 8;
      gload16(phik + gsrc, kls + (size_t)(cb + it * 64) * 8);
      gload16(vb   + gsrc, vls + (size_t)(cb + it * 64) * 8);
    }
    __syncthreads();
#pragma unroll 2
    for (int n = 0; n < 64; n++) {
      bf16x8 a8 = *(const bf16x8*)(kls + n * 128 + ek0);
      bf16x8 b8 = *(const bf16x8*)(vls + n * 128 + ev0);
      float a[8], b[8];
#pragma unroll
      for (int i = 0; i < 8; i++) { a[i] = (float)a8[i]; b[i] = (float)b8[i]; }
#pragma unroll
      for (int i = 0; i < 8; i++)
#pragma unroll
        for (int j = 0; j < 8; j++) acc[i][j] += a[i] * b[j];
    }
  }
#pragma unroll
  for (int i = 0; i < 8; i++)
#pragma unroll
    for (int j = 0; j < 8; j++)
      atomicAdd(&Mf[(size_t)h * 16384 + (ek0 + i) * 128 + ev0 + j], acc[i][j]);
}

// z[col] = sum_n phik[n][col]  (memory-bound column sum; col is head-major = h*128+e)
__global__ void zsum_kernel(const bf16_t* __restrict__ phik, float* __restrict__ z) {
  int col = blockIdx.x * 256 + threadIdx.x;   // grid.x = 4
  int n0 = blockIdx.y * 256;                  // grid.y = 64
  float s = 0.f;
  for (int n = 0; n < 256; ++n) s += (float)phik[(size_t)(n0 + n) * 1024 + col];
  atomicAdd(&z[col], s);
}

// Mbt[h][e][d] = (bf16) Mf[h][d][e]
__global__ void castM_kernel(const float* __restrict__ Mf, bf16_t* __restrict__ Mbt) {
  int i = blockIdx.x * 256 + threadIdx.x;    // 8*128*128 total
  int h = i >> 14, rem = i & 16383, d = rem >> 7, e = rem & 127;
  Mbt[(size_t)h * 16384 + e * 128 + d] = (bf16_t)Mf[i];
}

// ---------------- attention num/den/t  (t = (phiq @ kvsum) / (phiq . z + eps)) ----------------

__global__ __launch_bounds__(256, 2)
void attn_t_kernel(const bf16_t* __restrict__ phiq, const bf16_t* __restrict__ Mbt,
                   const float* __restrict__ z, bf16_t* __restrict__ tout)
{
  __shared__ bf16_t As[64 * 128];   // phiq rows (this block's 64 rows, head h's 128 k-cols)
  __shared__ bf16_t Bs[128 * 128];  // Mbt[h] : [e][d]
  __shared__ float  zs[128];
  __shared__ float  dens[64];
  int h = blockIdx.y, row0 = blockIdx.x * 64;
  int tid = threadIdx.x, lane = tid & 63, wave = tid >> 6;
  int wr = (wave >> 1) * 32, wc = (wave & 1) * 64;
  int l15 = lane & 15, g = lane >> 4;

#pragma unroll
  for (int it = 0; it < 4; ++it) {          // A: 64x128 = 1024 chunks
    int ch = it * 256 + tid;
    int r = ch >> 4, c8 = ch & 15;
    int cs = c8 ^ (r & 7);
    *(bf16x8*)(As + r * 128 + cs * 8) = *(const bf16x8*)(phiq + (size_t)(row0 + r) * 1024 + h * 128 + c8 * 8);
  }
#pragma unroll
  for (int it = 0; it < 8; ++it) {          // B: 128x128 = 2048 chunks
    int ch = it * 256 + tid;
    int r = ch >> 4, c8 = ch & 15;
    int cs = c8 ^ (r & 7);
    *(bf16x8*)(Bs + r * 128 + cs * 8) = *(const bf16x8*)(Mbt + (size_t)h * 16384 + ch * 8);
  }
  if (tid < 128) zs[tid] = z[h * 128 + tid];
  __syncthreads();

  f32x4 acc[2][4] = {};
#pragma unroll
  for (int ks = 0; ks < 128; ks += 32) {
    bf16x8 af[2], bfr[4];
#pragma unroll
    for (int i = 0; i < 2; i++) af[i]  = ldsfrag(As, wr + i * 16 + l15, 256, ks * 2 + 8 * g);
#pragma unroll
    for (int j = 0; j < 4; j++) bfr[j] = ldsfrag(Bs, wc + j * 16 + l15, 256, ks * 2 + 8 * g);
#pragma unroll
    for (int i = 0; i < 2; i++)
#pragma unroll
      for (int j = 0; j < 4; j++)
        acc[i][j] = __builtin_amdgcn_mfma_f32_16x16x32_bf16(af[i], bfr[j], acc[i][j], 0, 0, 0);
  }

  if (tid < 64) {                            // den for this block's 64 rows (skewed, swizzle-aware)
    float s = 0.f;
    const char* p = (const char*)As + tid * 256;
    int sw = (tid & 7) << 4;
    for (int d0 = 0; d0 < 128; ++d0) {
      int d = (d0 + tid) & 127;
      bf16_t kv = *(const bf16_t*)(p + ((2 * d) ^ sw));
      s += (float)kv * zs[d];
    }
    dens[tid] = s;
  }
  __syncthreads();

#pragma unroll
  for (int i = 0; i < 2; i++) {
    int lr = wr + i * 16 + g * 4;
#pragma unroll
    for (int j = 0; j < 4; j++) {
      int col = h * 128 + wc + j * 16 + l15;
      f32x4 v = acc[i][j];
#pragma unroll
      for (int rr = 0; rr < 4; rr++) {
        float den = dens[lr + rr] + 1e-6f;
        tout[(size_t)(row0 + lr + rr) * 1024 + col] = (bf16_t)(v[rr] / den);
      }
    }
  }
}

// ---------------- LayerNorms ----------------

// y = LN(unpermute(t) + x) * g + b   (y bf16, natural layout)
__global__ __launch_bounds__(256, 2)
void ln1_kernel(const bf16_t* __restrict__ t, const float* __restrict__ x,
                const float* __restrict__ gma, const float* __restrict__ bta,
                bf16_t* __restrict__ y)
{
  __shared__ float s[1024];
  __shared__ float rsum[4], rsq[4];
  int n = blockIdx.x, tid = threadIdx.x;
#pragma unroll
  for (int k = 0; k < 4; k++) {
    int p = k * 256 + tid;
    float tv = (float)t[(size_t)n * 1024 + p];
    int c = ((p & 127) << 3) | (p >> 7);     // nat(p)
    s[c] = tv;
  }
  __syncthreads();
  float sum = 0.f, sq = 0.f, sv[4];
#pragma unroll
  for (int k = 0; k < 4; k++) {
    int c = k * 256 + tid;
    float v = s[c] + x[(size_t)n * 1024 + c];
    sv[k] = v; sum += v; sq += v * v;
  }
#pragma unroll
  for (int o = 32; o > 0; o >>= 1) { sum += __shfl_down(sum, o); sq += __shfl_down(sq, o); }
  if ((tid & 63) == 0) { rsum[tid >> 6] = sum; rsq[tid >> 6] = sq; }
  __syncthreads();
  sum = rsum[0] + rsum[1] + rsum[2] + rsum[3];
  sq  = rsq[0] + rsq[1] + rsq[2] + rsq[3];
  float mu = sum * (1.f / 1024.f);
  float var = sq * (1.f / 1024.f) - mu * mu;
  float rs = rsqrtf(var + 1e-5f);
#pragma unroll
  for (int k = 0; k < 4; k++) {
    int c = k * 256 + tid;
    y[(size_t)n * 1024 + c] = (bf16_t)((sv[k] - mu) * rs * gma[c] + bta[c]);
  }
}

// out = LN(f + y) * g + b   (f,y bf16 natural; out f32)
__global__ __launch_bounds__(256, 2)
void ln2_kernel(const bf16_t* __restrict__ f, const bf16_t* __restrict__ y,
                const float* __restrict__ gma, const float* __restrict__ bta,
                float* __restrict__ out)
{
  __shared__ float rsum[4], rsq[4];
  int n = blockIdx.x, tid = threadIdx.x;
  float sum = 0.f, sq = 0.f, sv[4];
#pragma unroll
  for (int k = 0; k < 4; k++) {
    int c = k * 256 + tid;
    float v = (float)f[(size_t)n * 1024 + c] + (float)y[(size_t)n * 1024 + c];
    sv[k] = v; sum += v; sq += v * v;
  }
#pragma unroll
  for (int o = 32; o > 0; o >>= 1) { sum += __shfl_down(sum, o); sq += __shfl_down(sq, o); }
  if ((tid & 63) == 0) { rsum[tid >> 6] = sum; rsq[tid >> 6] = sq; }
  __syncthreads();
  sum = rsum[0] + rsum[1] + rsum[2] + rsum[3];
  sq  = rsq[0] + rsq[1] + rsq[2] + rsq[3];
  float mu = sum * (1.f / 1024.f);
  float var = sq * (1.f / 1024.f) - mu * mu;
  float rs = rsqrtf(var + 1e-5f);
#pragma unroll
  for (int k = 0; k < 4; k++) {
    int c = k * 256 + tid;
    out[(size_t)n * 1024 + c] = (sv[k] - mu) * rs * gma[c] + bta[c];
  }
}

// ---------------- launcher ----------------

extern "C" void kernel_launch(void* const* d_in, const int* in_sizes, int n_in,
                              void* d_out, int out_size, void* d_ws, size_t ws_size,
                              hipStream_t stream)
{
  const float* x    = (const float*)d_in[0];
  const float* Wq   = (const float*)d_in[1];
  const float* Wkv  = (const float*)d_in[2];
  const float* g1   = (const float*)d_in[3];
  const float* bt1  = (const float*)d_in[4];
  const float* W1   = (const float*)d_in[5];
  const float* b1   = (const float*)d_in[6];
  const float* W2   = (const float*)d_in[7];
  const float* b2   = (const float*)d_in[8];
  const float* g2   = (const float*)d_in[9];
  const float* bt2  = (const float*)d_in[10];
  float* out = (float*)d_out;

  char* ws = (char*)d_ws;
  size_t off = 0;
  auto alloc = [&](size_t bytes) { void* p = ws + off; off += (bytes + 255) & ~(size_t)255; return p; };

  const size_t NC2 = (size_t)NROWS * CDIM * 2;          // 33.5 MB (bf16 [N][C])
  bf16_t* xb    = (bf16_t*)alloc(NC2);                  // xb, later reused as t
  bf16_t* wqkv  = (bf16_t*)alloc((size_t)3072 * 1024 * 2);
  bf16_t* w1bt  = (bf16_t*)alloc((size_t)1024 * 1024 * 2);
  bf16_t* w2bt  = (bf16_t*)alloc((size_t)1024 * 1024 * 2);
  bf16_t* phiq  = (bf16_t*)alloc(NC2);
  bf16_t* phik  = (bf16_t*)alloc(NC2);                  // later reused as h
  bf16_t* vbuf  = (bf16_t*)alloc(NC2);                  // later reused as f
  bf16_t* ybuf  = (bf16_t*)alloc(NC2);
  float*  Mf    = (float*)alloc(524288 + 4096);         // Mf[8][128][128] + z[1024]
  float*  zbuf  = Mf + 131072;
  bf16_t* Mbt   = (bf16_t*)alloc(262144);
  bf16_t* tbuf  = xb;                                   // alias (xb dead after QKV GEMM)
  bf16_t* hbuf  = phik;                                 // alias (phik dead after kvsum/zsum)
  bf16_t* fbuf  = vbuf;                                 // alias (v dead after kvsum)

  hipMemsetAsync(Mf, 0, 524288 + 4096, stream);

  cast_x_kernel<<<2048, 256, 0, stream>>>(x, xb, (long)NROWS * CDIM);
  prep_w_kernel<<<dim3(16, 16, 5), 256, 0, stream>>>(Wq, Wkv, W1, W2, wqkv, w1bt, w2bt);

  gemm_bt_kernel<0><<<dim3(128, 24), 256, 0, stream>>>(xb, wqkv, nullptr, phiq, phik, vbuf,
                                                       NROWS, 3072, 1024);
  kvsum_kernel<<<dim3(64, 8), 256, 0, stream>>>(phik, vbuf, Mf);
  zsum_kernel<<<dim3(4, 64), 256, 0, stream>>>(phik, zbuf);
  castM_kernel<<<512, 256, 0, stream>>>(Mf, Mbt);
  attn_t_kernel<<<dim3(256, 8), 256, 0, stream>>>(phiq, Mbt, zbuf, tbuf);
  ln1_kernel<<<NROWS, 256, 0, stream>>>(tbuf, x, g1, bt1, ybuf);

  gemm_bt_kernel<1><<<dim3(128, 8), 256, 0, stream>>>(ybuf, w1bt, b1, hbuf, nullptr, nullptr,
                                                      NROWS, 1024, 1024);
  gemm_bt_kernel<2><<<dim3(128, 8), 256, 0, stream>>>(hbuf, w2bt, b2, fbuf, nullptr, nullptr,
                                                      NROWS, 1024, 1024);
  ln2_kernel<<<NROWS, 256, 0, stream>>>(fbuf, ybuf, g2, bt2, out);
}

// Round 4
// 443.126 us; speedup vs baseline: 3.4888x; 1.5261x over previous
//
#include <hip/hip_runtime.h>
#include <hip/hip_bf16.h>
#include <cstdint>
#include <cstddef>

typedef __bf16 bf16_t;
typedef bf16_t bf16x4 __attribute__((ext_vector_type(4)));
typedef bf16_t bf16x8 __attribute__((ext_vector_type(8)));
typedef float f32x4 __attribute__((ext_vector_type(4)));

static constexpr int NROWS = 16384;
static constexpr int CDIM  = 1024;

// ---------------- helpers ----------------

// Async global->LDS 16B copy. LDS dest is WAVE-UNIFORM base; HW adds lane*16.
// Global src is PER-LANE -> swizzled LDS layouts are achieved by pre-swizzling
// the per-lane global address while keeping the LDS dest linear (rule #21).
__device__ __forceinline__ void gload16(const bf16_t* g, bf16_t* l) {
  __builtin_amdgcn_global_load_lds((const __attribute__((address_space(1))) void*)g,
                                   (__attribute__((address_space(3))) void*)l, 16, 0, 0);
}

// Fragment load for v_mfma_f32_16x16x32_bf16 from a row-major LDS tile whose
// 16B granules are XOR-swizzled: granule byte-address ^= (row&7)<<4.
// Lane(l15,g) holds A[row][ks+4g+{0..3}] and A[row][ks+4g+16+{0..3}].
__device__ __forceinline__ bf16x8 ldsfrag(const bf16_t* lds, int row, int ldbytes, int kbyte) {
  const char* p = (const char*)lds + row * ldbytes;
  int sw = (row & 7) << 4;
  union { bf16x4 h[2]; bf16x8 v; } u;
  u.h[0] = *(const bf16x4*)(p + ((kbyte) ^ sw));
  u.h[1] = *(const bf16x4*)(p + ((kbyte + 32) ^ sw));
  return u.v;
}

__device__ __forceinline__ float phi_fn(float v) {           // elu + 1
  return v > 0.f ? v + 1.f : expf(v);
}
__device__ __forceinline__ float gelu_fn(float v) {          // exact gelu
  return 0.5f * v * (1.f + erff(v * 0.70710678118654752f));
}

// ---------------- elementwise / prep ----------------

__global__ void cast_x_kernel(const float* __restrict__ x, bf16_t* __restrict__ xb, long n) {
  long i = (long)blockIdx.x * blockDim.x + threadIdx.x;
  long stride = (long)gridDim.x * blockDim.x;
  for (long e = i * 8; e < n; e += stride * 8) {
    float4 a = *(const float4*)(x + e);
    float4 b = *(const float4*)(x + e + 4);
    bf16x8 o;
    o[0] = (bf16_t)a.x; o[1] = (bf16_t)a.y; o[2] = (bf16_t)a.z; o[3] = (bf16_t)a.w;
    o[4] = (bf16_t)b.x; o[5] = (bf16_t)b.y; o[6] = (bf16_t)b.z; o[7] = (bf16_t)b.w;
    *(bf16x8*)(xb + e) = o;
  }
}

// Transpose-cast weights to column-major bf16 (Bt[n][k]); modes 0-2 also apply
// the head-major column permutation perm(c) = (c%8)*128 + c/8.
__global__ void prep_w_kernel(const float* __restrict__ Wq, const float* __restrict__ Wkv,
                              const float* __restrict__ W1, const float* __restrict__ W2,
                              bf16_t* __restrict__ wqkv_bt, bf16_t* __restrict__ w1bt,
                              bf16_t* __restrict__ w2bt) {
  __shared__ float tile[64][65];
  int mode = blockIdx.z;
  const float* src; int ld; bf16_t* dst; int permute;
  if (mode == 0)      { src = Wq;          ld = 1024; dst = wqkv_bt;                       permute = 1; }
  else if (mode == 1) { src = Wkv;         ld = 2048; dst = wqkv_bt + (size_t)1024 * 1024; permute = 1; }
  else if (mode == 2) { src = Wkv + 1024;  ld = 2048; dst = wqkv_bt + (size_t)2048 * 1024; permute = 1; }
  else if (mode == 3) { src = W1;          ld = 1024; dst = w1bt;                          permute = 0; }
  else                { src = W2;          ld = 1024; dst = w2bt;                          permute = 0; }
  int r0 = blockIdx.x * 64, c0 = blockIdx.y * 64;
  int tid = threadIdx.x;
#pragma unroll
  for (int i = 0; i < 16; i++) {
    int idx = i * 256 + tid; int rr = idx >> 6, cc = idx & 63;
    tile[rr][cc] = src[(size_t)(r0 + rr) * ld + c0 + cc];
  }
  __syncthreads();
#pragma unroll
  for (int i = 0; i < 16; i++) {
    int idx = i * 256 + tid; int cc = idx >> 6, rr = idx & 63;
    int c = c0 + cc;
    int a = permute ? (((c & 7) << 7) | (c >> 3)) : c;
    dst[(size_t)a * 1024 + r0 + rr] = (bf16_t)tile[rr][cc];
  }
}

// ---------------- main GEMM:  out = A[M][K] @ Bt[N][K]^T ----------------
// m97 staging (global_load_lds width-16) + m201-style swizzle: LDS dest linear,
// global source column pre-XOR'd (c16 ^= r&7), reads via swizzled ldsfrag.
// MODE 0: QKV (N=3072): cols [0,1024) -> phi -> o0; [1024,2048) -> phi -> o1; [2048,3072) -> o2
// MODE 1: FFN1: gelu(acc + bias[col]) -> o0
// MODE 2: FFN2: acc + bias[col] -> o0

template<int MODE>
__global__ __launch_bounds__(256, 3)
void gemm_bt_kernel(const bf16_t* __restrict__ A, const bf16_t* __restrict__ Bt,
                    const float* __restrict__ bias,
                    bf16_t* __restrict__ o0, bf16_t* __restrict__ o1, bf16_t* __restrict__ o2,
                    int M, int N, int K)
{
  __shared__ bf16_t As[128 * 64];
  __shared__ bf16_t Bs[128 * 64];
  const int tid  = threadIdx.x;
  const int lane = tid & 63;
  const int wave = tid >> 6;
  const int wr = (wave >> 1) * 64, wc = (wave & 1) * 64;
  const int l15 = lane & 15, g = lane >> 4;
  const int row0 = blockIdx.x * 128, col0 = blockIdx.y * 128;
  const int cb = wave * 256;                 // this wave's 256-chunk slice of 1024
  f32x4 acc[4][4] = {};

  for (int kt = 0; kt < K; kt += 64) {
    __syncthreads();                         // prior iter's LDS reads done
#pragma unroll
    for (int it = 0; it < 4; ++it) {
      int ch = cb + it * 64 + lane;          // LDS 16B-chunk id (linear dest)
      int r = ch >> 3;
      int csrc = (ch & 7) ^ (r & 7);         // inverse-swizzled source column
      gload16(A  + (size_t)(row0 + r) * K + kt + csrc * 8, As + (size_t)(cb + it * 64) * 8);
      gload16(Bt + (size_t)(col0 + r) * K + kt + csrc * 8, Bs + (size_t)(cb + it * 64) * 8);
    }
    __syncthreads();                         // compiler drains vmcnt before barrier
#pragma unroll
    for (int ks = 0; ks < 64; ks += 32) {
      bf16x8 af[4], bfr[4];
#pragma unroll
      for (int i = 0; i < 4; i++) af[i]  = ldsfrag(As, wr + i * 16 + l15, 128, ks * 2 + 8 * g);
#pragma unroll
      for (int i = 0; i < 4; i++) bfr[i] = ldsfrag(Bs, wc + i * 16 + l15, 128, ks * 2 + 8 * g);
#pragma unroll
      for (int i = 0; i < 4; i++)
#pragma unroll
        for (int j = 0; j < 4; j++)
          acc[i][j] = __builtin_amdgcn_mfma_f32_16x16x32_bf16(af[i], bfr[j], acc[i][j], 0, 0, 0);
    }
  }

  // epilogue: D col = l&15, row = 4*(lane>>4) + reg
#pragma unroll
  for (int i = 0; i < 4; i++) {
    int rbase = row0 + wr + i * 16 + g * 4;
#pragma unroll
    for (int j = 0; j < 4; j++) {
      int col = col0 + wc + j * 16 + l15;
      f32x4 v = acc[i][j];
      if constexpr (MODE == 0) {
        int seg = col >> 10;
        int cl  = col & 1023;
        bf16_t* dst = (seg == 0) ? o0 : (seg == 1 ? o1 : o2);
#pragma unroll
        for (int rr = 0; rr < 4; rr++) {
          float val = v[rr];
          if (seg != 2) val = phi_fn(val);
          dst[(size_t)(rbase + rr) * 1024 + cl] = (bf16_t)val;
        }
      } else if constexpr (MODE == 1) {
        float bv = bias[col];
#pragma unroll
        for (int rr = 0; rr < 4; rr++)
          o0[(size_t)(rbase + rr) * 1024 + col] = (bf16_t)gelu_fn(v[rr] + bv);
      } else {
        float bv = bias[col];
#pragma unroll
        for (int rr = 0; rr < 4; rr++)
          o0[(size_t)(rbase + rr) * 1024 + col] = (bf16_t)(v[rr] + bv);
      }
    }
  }
}

// ---------------- kv_sum partials (split-K VALU outer product, NO atomics) ----------------
// 512 blocks (64 n-chunks x 8 heads), 256 rows each. Each block writes a private
// 128x128 f32 partial tile P[h][c] and 128 z-partials Zp[h][c] (z folded in).

__global__ __launch_bounds__(256, 4)
void kvsum_kernel(const bf16_t* __restrict__ phik, const bf16_t* __restrict__ vb,
                  float* __restrict__ P, float* __restrict__ Zp)
{
  __shared__ bf16_t kls[64 * 128];
  __shared__ bf16_t vls[64 * 128];
  const int h = blockIdx.y;
  const int c = blockIdx.x;
  const int n0 = c * 256;
  const int tid = threadIdx.x;
  const int lane = tid & 63, wave = tid >> 6;
  const int cb = wave * 256;
  const int ek0 = (tid >> 4) * 8, ev0 = (tid & 15) * 8;
  float acc[8][8] = {};
  float zacc[8] = {};

  for (int nt = 0; nt < 4; ++nt) {
    __syncthreads();
#pragma unroll
    for (int it = 0; it < 4; ++it) {
      int ch = cb + it * 64 + lane;          // 1024 chunks of 16B per matrix
      int r = ch >> 4, c16 = ch & 15;
      const size_t gsrc = (size_t)(n0 + nt * 64 + r) * 1024 + h * 128 + c16 * 8;
      gload16(phik + gsrc, kls + (size_t)(cb + it * 64) * 8);
      gload16(vb   + gsrc, vls + (size_t)(cb + it * 64) * 8);
    }
    __syncthreads();
#pragma unroll 2
    for (int n = 0; n < 64; n++) {
      bf16x8 a8 = *(const bf16x8*)(kls + n * 128 + ek0);
      bf16x8 b8 = *(const bf16x8*)(vls + n * 128 + ev0);
      float a[8], b[8];
#pragma unroll
      for (int i = 0; i < 8; i++) { a[i] = (float)a8[i]; b[i] = (float)b8[i]; }
      if ((tid & 15) == 0) {
#pragma unroll
        for (int i = 0; i < 8; i++) zacc[i] += a[i];
      }
#pragma unroll
      for (int i = 0; i < 8; i++)
#pragma unroll
        for (int j = 0; j < 8; j++) acc[i][j] += a[i] * b[j];
    }
  }
  float* pb = P + ((size_t)h * 64 + c) * 16384;
#pragma unroll
  for (int i = 0; i < 8; i++) {
    *(float4*)(pb + (ek0 + i) * 128 + ev0)     = *(float4*)&acc[i][0];
    *(float4*)(pb + (ek0 + i) * 128 + ev0 + 4) = *(float4*)&acc[i][4];
  }
  if ((tid & 15) == 0) {
    float* zb = Zp + ((size_t)h * 64 + c) * 128;
#pragma unroll
    for (int i = 0; i < 8; i++) zb[ek0 + i] = zacc[i];
  }
}

// Reduce 64 partials per head -> Mbt[h][e][d] (bf16, transposed) and z[h*128+d].
__global__ void reduce_kvsum_kernel(const float* __restrict__ P, const float* __restrict__ Zp,
                                    bf16_t* __restrict__ Mbt, float* __restrict__ z)
{
  int i = blockIdx.x * 256 + threadIdx.x;    // [0, 131072)
  int h = i >> 14, d = (i >> 7) & 127, e = i & 127;
  const float* p = P + (size_t)h * 64 * 16384 + (size_t)d * 128 + e;
  float s = 0.f;
#pragma unroll 8
  for (int c = 0; c < 64; ++c) s += p[(size_t)c * 16384];
  Mbt[(size_t)h * 16384 + e * 128 + d] = (bf16_t)s;
  if (i < 1024) {
    int hh = i >> 7, dd = i & 127;
    const float* q = Zp + (size_t)hh * 64 * 128 + dd;
    float sz = 0.f;
#pragma unroll 8
    for (int c = 0; c < 64; ++c) sz += q[c * 128];
    z[i] = sz;
  }
}

// ---------------- attention num/den/t  (t = (phiq @ kvsum) / (phiq . z + eps)) ----------------

__global__ __launch_bounds__(256, 2)
void attn_t_kernel(const bf16_t* __restrict__ phiq, const bf16_t* __restrict__ Mbt,
                   const float* __restrict__ z, bf16_t* __restrict__ tout)
{
  __shared__ bf16_t As[64 * 128];   // phiq rows (this block's 64 rows, head h's 128 k-cols)
  __shared__ bf16_t Bs[128 * 128];  // Mbt[h] : [e][d]
  __shared__ float  zs[128];
  __shared__ float  dens[64];
  int h = blockIdx.y, row0 = blockIdx.x * 64;
  int tid = threadIdx.x, lane = tid & 63, wave = tid >> 6;
  int wr = (wave >> 1) * 32, wc = (wave & 1) * 64;
  int l15 = lane & 15, g = lane >> 4;

#pragma unroll
  for (int it = 0; it < 4; ++it) {          // A: 64x128 = 1024 chunks
    int ch = it * 256 + tid;
    int r = ch >> 4, c8 = ch & 15;
    int cs = c8 ^ (r & 7);
    *(bf16x8*)(As + r * 128 + cs * 8) = *(const bf16x8*)(phiq + (size_t)(row0 + r) * 1024 + h * 128 + c8 * 8);
  }
#pragma unroll
  for (int it = 0; it < 8; ++it) {          // B: 128x128 = 2048 chunks
    int ch = it * 256 + tid;
    int r = ch >> 4, c8 = ch & 15;
    int cs = c8 ^ (r & 7);
    *(bf16x8*)(Bs + r * 128 + cs * 8) = *(const bf16x8*)(Mbt + (size_t)h * 16384 + ch * 8);
  }
  if (tid < 128) zs[tid] = z[h * 128 + tid];
  __syncthreads();

  f32x4 acc[2][4] = {};
#pragma unroll
  for (int ks = 0; ks < 128; ks += 32) {
    bf16x8 af[2], bfr[4];
#pragma unroll
    for (int i = 0; i < 2; i++) af[i]  = ldsfrag(As, wr + i * 16 + l15, 256, ks * 2 + 8 * g);
#pragma unroll
    for (int j = 0; j < 4; j++) bfr[j] = ldsfrag(Bs, wc + j * 16 + l15, 256, ks * 2 + 8 * g);
#pragma unroll
    for (int i = 0; i < 2; i++)
#pragma unroll
      for (int j = 0; j < 4; j++)
        acc[i][j] = __builtin_amdgcn_mfma_f32_16x16x32_bf16(af[i], bfr[j], acc[i][j], 0, 0, 0);
  }

  if (tid < 64) {                            // den for this block's 64 rows (skewed, swizzle-aware)
    float s = 0.f;
    const char* p = (const char*)As + tid * 256;
    int sw = (tid & 7) << 4;
    for (int d0 = 0; d0 < 128; ++d0) {
      int d = (d0 + tid) & 127;
      bf16_t kv = *(const bf16_t*)(p + ((2 * d) ^ sw));
      s += (float)kv * zs[d];
    }
    dens[tid] = s;
  }
  __syncthreads();

#pragma unroll
  for (int i = 0; i < 2; i++) {
    int lr = wr + i * 16 + g * 4;
#pragma unroll
    for (int j = 0; j < 4; j++) {
      int col = h * 128 + wc + j * 16 + l15;
      f32x4 v = acc[i][j];
#pragma unroll
      for (int rr = 0; rr < 4; rr++) {
        float den = dens[lr + rr] + 1e-6f;
        tout[(size_t)(row0 + lr + rr) * 1024 + col] = (bf16_t)(v[rr] / den);
      }
    }
  }
}

// ---------------- LayerNorms ----------------

// y = LN(unpermute(t) + x) * g + b   (y bf16, natural layout)
__global__ __launch_bounds__(256, 2)
void ln1_kernel(const bf16_t* __restrict__ t, const float* __restrict__ x,
                const float* __restrict__ gma, const float* __restrict__ bta,
                bf16_t* __restrict__ y)
{
  __shared__ float s[1024];
  __shared__ float rsum[4], rsq[4];
  int n = blockIdx.x, tid = threadIdx.x;
#pragma unroll
  for (int k = 0; k < 4; k++) {
    int p = k * 256 + tid;
    float tv = (float)t[(size_t)n * 1024 + p];
    int c = ((p & 127) << 3) | (p >> 7);     // nat(p)
    s[c] = tv;
  }
  __syncthreads();
  float sum = 0.f, sq = 0.f, sv[4];
#pragma unroll
  for (int k = 0; k < 4; k++) {
    int c = k * 256 + tid;
    float v = s[c] + x[(size_t)n * 1024 + c];
    sv[k] = v; sum += v; sq += v * v;
  }
#pragma unroll
  for (int o = 32; o > 0; o >>= 1) { sum += __shfl_down(sum, o); sq += __shfl_down(sq, o); }
  if ((tid & 63) == 0) { rsum[tid >> 6] = sum; rsq[tid >> 6] = sq; }
  __syncthreads();
  sum = rsum[0] + rsum[1] + rsum[2] + rsum[3];
  sq  = rsq[0] + rsq[1] + rsq[2] + rsq[3];
  float mu = sum * (1.f / 1024.f);
  float var = sq * (1.f / 1024.f) - mu * mu;
  float rs = rsqrtf(var + 1e-5f);
#pragma unroll
  for (int k = 0; k < 4; k++) {
    int c = k * 256 + tid;
    y[(size_t)n * 1024 + c] = (bf16_t)((sv[k] - mu) * rs * gma[c] + bta[c]);
  }
}

// out = LN(f + y) * g + b   (f,y bf16 natural; out f32)
__global__ __launch_bounds__(256, 2)
void ln2_kernel(const bf16_t* __restrict__ f, const bf16_t* __restrict__ y,
                const float* __restrict__ gma, const float* __restrict__ bta,
                float* __restrict__ out)
{
  __shared__ float rsum[4], rsq[4];
  int n = blockIdx.x, tid = threadIdx.x;
  float sum = 0.f, sq = 0.f, sv[4];
#pragma unroll
  for (int k = 0; k < 4; k++) {
    int c = k * 256 + tid;
    float v = (float)f[(size_t)n * 1024 + c] + (float)y[(size_t)n * 1024 + c];
    sv[k] = v; sum += v; sq += v * v;
  }
#pragma unroll
  for (int o = 32; o > 0; o >>= 1) { sum += __shfl_down(sum, o); sq += __shfl_down(sq, o); }
  if ((tid & 63) == 0) { rsum[tid >> 6] = sum; rsq[tid >> 6] = sq; }
  __syncthreads();
  sum = rsum[0] + rsum[1] + rsum[2] + rsum[3];
  sq  = rsq[0] + rsq[1] + rsq[2] + rsq[3];
  float mu = sum * (1.f / 1024.f);
  float var = sq * (1.f / 1024.f) - mu * mu;
  float rs = rsqrtf(var + 1e-5f);
#pragma unroll
  for (int k = 0; k < 4; k++) {
    int c = k * 256 + tid;
    out[(size_t)n * 1024 + c] = (sv[k] - mu) * rs * gma[c] + bta[c];
  }
}

// ---------------- launcher ----------------

extern "C" void kernel_launch(void* const* d_in, const int* in_sizes, int n_in,
                              void* d_out, int out_size, void* d_ws, size_t ws_size,
                              hipStream_t stream)
{
  const float* x    = (const float*)d_in[0];
  const float* Wq   = (const float*)d_in[1];
  const float* Wkv  = (const float*)d_in[2];
  const float* g1   = (const float*)d_in[3];
  const float* bt1  = (const float*)d_in[4];
  const float* W1   = (const float*)d_in[5];
  const float* b1   = (const float*)d_in[6];
  const float* W2   = (const float*)d_in[7];
  const float* b2   = (const float*)d_in[8];
  const float* g2   = (const float*)d_in[9];
  const float* bt2  = (const float*)d_in[10];
  float* out = (float*)d_out;

  char* ws = (char*)d_ws;
  size_t off = 0;
  auto alloc = [&](size_t bytes) { void* p = ws + off; off += (bytes + 255) & ~(size_t)255; return p; };

  const size_t NC2 = (size_t)NROWS * CDIM * 2;          // 33.5 MB (bf16 [N][C])
  bf16_t* xb    = (bf16_t*)alloc(NC2);                  // xb; later: kvsum partials P; later: t
  bf16_t* wqkv  = (bf16_t*)alloc((size_t)3072 * 1024 * 2);
  bf16_t* w1bt  = (bf16_t*)alloc((size_t)1024 * 1024 * 2);
  bf16_t* w2bt  = (bf16_t*)alloc((size_t)1024 * 1024 * 2);
  bf16_t* phiq  = (bf16_t*)alloc(NC2);
  bf16_t* phik  = (bf16_t*)alloc(NC2);                  // later reused as h
  bf16_t* vbuf  = (bf16_t*)alloc(NC2);                  // later reused as f
  bf16_t* ybuf  = (bf16_t*)alloc(NC2);
  float*  Zp    = (float*)alloc(262144 + 4096);         // Zp[8][64][128] + z[1024]
  float*  zbuf  = Zp + 65536;
  bf16_t* Mbt   = (bf16_t*)alloc(262144);
  float*  Pbuf  = (float*)xb;                           // alias: 8*64*16384 f32 = exactly NC2 bytes
  bf16_t* tbuf  = xb;                                   // alias (P dead after reduce)
  bf16_t* hbuf  = phik;                                 // alias (phik dead after kvsum)
  bf16_t* fbuf  = vbuf;                                 // alias (v dead after kvsum)

  cast_x_kernel<<<2048, 256, 0, stream>>>(x, xb, (long)NROWS * CDIM);
  prep_w_kernel<<<dim3(16, 16, 5), 256, 0, stream>>>(Wq, Wkv, W1, W2, wqkv, w1bt, w2bt);

  gemm_bt_kernel<0><<<dim3(128, 24), 256, 0, stream>>>(xb, wqkv, nullptr, phiq, phik, vbuf,
                                                       NROWS, 3072, 1024);
  kvsum_kernel<<<dim3(64, 8), 256, 0, stream>>>(phik, vbuf, Pbuf, Zp);
  reduce_kvsum_kernel<<<512, 256, 0, stream>>>(Pbuf, Zp, Mbt, zbuf);
  attn_t_kernel<<<dim3(256, 8), 256, 0, stream>>>(phiq, Mbt, zbuf, tbuf);
  ln1_kernel<<<NROWS, 256, 0, stream>>>(tbuf, x, g1, bt1, ybuf);

  gemm_bt_kernel<1><<<dim3(128, 8), 256, 0, stream>>>(ybuf, w1bt, b1, hbuf, nullptr, nullptr,
                                                      NROWS, 1024, 1024);
  gemm_bt_kernel<2><<<dim3(128, 8), 256, 0, stream>>>(hbuf, w2bt, b2, fbuf, nullptr, nullptr,
                                                      NROWS, 1024, 1024);
  ln2_kernel<<<NROWS, 256, 0, stream>>>(fbuf, ybuf, g2, bt2, out);
}

// Round 5
// 360.483 us; speedup vs baseline: 4.2886x; 1.2293x over previous
//
#include <hip/hip_runtime.h>
#include <hip/hip_bf16.h>
#include <cstdint>
#include <cstddef>

typedef __bf16 bf16_t;
typedef bf16_t bf16x4 __attribute__((ext_vector_type(4)));
typedef bf16_t bf16x8 __attribute__((ext_vector_type(8)));
typedef float f32x4 __attribute__((ext_vector_type(4)));

static constexpr int NROWS = 16384;
static constexpr int CDIM  = 1024;

// ---------------- K-permutation (contiguous MFMA fragments) ----------------
// All bf16 GEMM inputs store logical k at position p6(k) within each 64-group,
// so fragment (ks,g) = storage [ks*32+8g .. +7] = one 16B ds_read_b128.
// p6: k=[b5 b4 b3 b2 b1 b0] -> s=[b5 b3 b2 b4 b1 b0].
__device__ __forceinline__ int p6(int k) {
  return (k & 32) | ((k & 12) << 1) | ((k & 16) >> 2) | (k & 3);
}
__device__ __forceinline__ int p6i(int s) {
  return (s & 32) | ((s & 4) << 2) | ((s & 24) >> 1) | (s & 3);
}
__device__ __forceinline__ int permc(int c) {        // within-64 perm of a wider index
  return (c & ~63) | p6(c & 63);
}

// ---------------- helpers ----------------

// Async global->LDS 16B copy. LDS dest is WAVE-UNIFORM base; HW adds lane*16.
__device__ __forceinline__ void gload16(const bf16_t* g, bf16_t* l) {
  __builtin_amdgcn_global_load_lds((const __attribute__((address_space(1))) void*)g,
                                   (__attribute__((address_space(3))) void*)l, 16, 0, 0);
}

// Single-b128 fragment load from a row-major LDS tile whose 16B granules are
// XOR-swizzled: granule byte-addr ^= (row&7)<<4. kbyte is a multiple of 16.
__device__ __forceinline__ bf16x8 ldsf128(const bf16_t* lds, int row, int ldbytes, int kbyte) {
  const char* p = (const char*)lds + row * ldbytes + (kbyte ^ ((row & 7) << 4));
  return *(const bf16x8*)p;
}

__device__ __forceinline__ float phi_fn(float v) {           // elu + 1
  return v > 0.f ? v + 1.f : expf(v);
}
__device__ __forceinline__ float gelu_fn(float v) {          // exact gelu
  return 0.5f * v * (1.f + erff(v * 0.70710678118654752f));
}

// ---------------- elementwise / prep ----------------

// xb[row][PERM(c)] = (bf16) x[row][c]  -- written chunk-wise (8 elems/chunk).
__global__ void cast_x_kernel(const float* __restrict__ x, bf16_t* __restrict__ xb, long nchunks) {
  long i = (long)blockIdx.x * blockDim.x + threadIdx.x;
  long stride = (long)gridDim.x * blockDim.x;
  for (long c = i; c < nchunks; c += stride) {
    long row = c >> 7;
    int p0 = (int)(c & 127) << 3;            // storage position of this 8-elem chunk
    int group = p0 & ~63;
    int ccl = (p0 >> 3) & 7;                 // chunk within 64-group
    int klo = ((ccl & 4) << 3) | ((ccl & 3) << 2);   // logical k of elems 0-3 (4-7 = +16)
    const float* src = x + row * 1024 + group + klo;
    float4 a = *(const float4*)src;
    float4 b = *(const float4*)(src + 16);
    bf16x8 o;
    o[0] = (bf16_t)a.x; o[1] = (bf16_t)a.y; o[2] = (bf16_t)a.z; o[3] = (bf16_t)a.w;
    o[4] = (bf16_t)b.x; o[5] = (bf16_t)b.y; o[6] = (bf16_t)b.z; o[7] = (bf16_t)b.w;
    *(bf16x8*)(xb + row * 1024 + p0) = o;
  }
}

// Transpose-cast weights to column-major bf16 (Bt[n][k_perm]); modes 0-2 also
// apply the head-major column permutation perm(c) = (c%8)*128 + c/8.
__global__ void prep_w_kernel(const float* __restrict__ Wq, const float* __restrict__ Wkv,
                              const float* __restrict__ W1, const float* __restrict__ W2,
                              bf16_t* __restrict__ wqkv_bt, bf16_t* __restrict__ w1bt,
                              bf16_t* __restrict__ w2bt) {
  __shared__ float tile[64][65];
  int mode = blockIdx.z;
  const float* src; int ld; bf16_t* dst; int permute;
  if (mode == 0)      { src = Wq;          ld = 1024; dst = wqkv_bt;                       permute = 1; }
  else if (mode == 1) { src = Wkv;         ld = 2048; dst = wqkv_bt + (size_t)1024 * 1024; permute = 1; }
  else if (mode == 2) { src = Wkv + 1024;  ld = 2048; dst = wqkv_bt + (size_t)2048 * 1024; permute = 1; }
  else if (mode == 3) { src = W1;          ld = 1024; dst = w1bt;                          permute = 0; }
  else                { src = W2;          ld = 1024; dst = w2bt;                          permute = 0; }
  int r0 = blockIdx.x * 64, c0 = blockIdx.y * 64;
  int tid = threadIdx.x;
#pragma unroll
  for (int i = 0; i < 16; i++) {
    int idx = i * 256 + tid; int rr = idx >> 6, cc = idx & 63;
    tile[rr][cc] = src[(size_t)(r0 + rr) * ld + c0 + cc];
  }
  __syncthreads();
#pragma unroll
  for (int i = 0; i < 16; i++) {
    int idx = i * 256 + tid; int cc = idx >> 6, rr = idx & 63;
    int c = c0 + cc;
    int a = permute ? (((c & 7) << 7) | (c >> 3)) : c;
    dst[(size_t)a * 1024 + r0 + p6(rr)] = (bf16_t)tile[rr][cc];
  }
}

// ---------------- main GEMM:  out = A[M][Kp] @ Bt[N][Kp]^T ----------------
// MODE 0: QKV (N=3072): cols [0,1024) -> phi -> o0(perm'd); [1024,2048) -> phi -> o1; [2048,3072) -> o2
// MODE 1: FFN1: gelu(acc + bias) -> o0 at PERM'd col (FFN2's k-dim)
// MODE 2: FFN2: acc + bias -> o0 natural

template<int MODE>
__global__ __launch_bounds__(256, 4)
void gemm_bt_kernel(const bf16_t* __restrict__ A, const bf16_t* __restrict__ Bt,
                    const float* __restrict__ bias,
                    bf16_t* __restrict__ o0, bf16_t* __restrict__ o1, bf16_t* __restrict__ o2,
                    int M, int N, int K)
{
  __shared__ bf16_t As[128 * 64];
  __shared__ bf16_t Bs[128 * 64];
  const int tid  = threadIdx.x;
  const int lane = tid & 63;
  const int wave = tid >> 6;
  const int wr = (wave >> 1) * 64, wc = (wave & 1) * 64;
  const int l15 = lane & 15, g = lane >> 4;
  const int row0 = blockIdx.x * 128, col0 = blockIdx.y * 128;
  const int cb = wave * 256;                 // this wave's 256-chunk slice of 1024
  f32x4 acc[4][4] = {};

  for (int kt = 0; kt < K; kt += 64) {
    __syncthreads();                         // prior iter's LDS reads done
#pragma unroll
    for (int it = 0; it < 4; ++it) {
      int ch = cb + it * 64 + lane;          // LDS 16B-chunk id (linear dest)
      int r = ch >> 3;
      int csrc = (ch & 7) ^ (r & 7);         // inverse-swizzled source granule
      gload16(A  + (size_t)(row0 + r) * K + kt + csrc * 8, As + (size_t)(cb + it * 64) * 8);
      gload16(Bt + (size_t)(col0 + r) * K + kt + csrc * 8, Bs + (size_t)(cb + it * 64) * 8);
    }
    __syncthreads();
#pragma unroll
    for (int ks = 0; ks < 2; ++ks) {
      bf16x8 af[4], bfr[4];
#pragma unroll
      for (int i = 0; i < 4; i++) af[i]  = ldsf128(As, wr + i * 16 + l15, 128, ks * 64 + 16 * g);
#pragma unroll
      for (int i = 0; i < 4; i++) bfr[i] = ldsf128(Bs, wc + i * 16 + l15, 128, ks * 64 + 16 * g);
#pragma unroll
      for (int i = 0; i < 4; i++)
#pragma unroll
        for (int j = 0; j < 4; j++)
          acc[i][j] = __builtin_amdgcn_mfma_f32_16x16x32_bf16(af[i], bfr[j], acc[i][j], 0, 0, 0);
    }
  }

  // epilogue: D col = l&15, row = 4*(lane>>4) + reg
#pragma unroll
  for (int i = 0; i < 4; i++) {
    int rbase = row0 + wr + i * 16 + g * 4;
#pragma unroll
    for (int j = 0; j < 4; j++) {
      int col = col0 + wc + j * 16 + l15;
      f32x4 v = acc[i][j];
      if constexpr (MODE == 0) {
        int seg = col >> 10;
        int cl  = permc(col & 1023);         // storage-perm'd (consumers' k-dim)
        bf16_t* dst = (seg == 0) ? o0 : (seg == 1 ? o1 : o2);
#pragma unroll
        for (int rr = 0; rr < 4; rr++) {
          float val = v[rr];
          if (seg != 2) val = phi_fn(val);
          dst[(size_t)(rbase + rr) * 1024 + cl] = (bf16_t)val;
        }
      } else if constexpr (MODE == 1) {
        float bv = bias[col];
        int cs = permc(col);                 // FFN2's k-dim
#pragma unroll
        for (int rr = 0; rr < 4; rr++)
          o0[(size_t)(rbase + rr) * 1024 + cs] = (bf16_t)gelu_fn(v[rr] + bv);
      } else {
        float bv = bias[col];
#pragma unroll
        for (int rr = 0; rr < 4; rr++)
          o0[(size_t)(rbase + rr) * 1024 + col] = (bf16_t)(v[rr] + bv);
      }
    }
  }
}

// ---------------- kv_sum partials (split-K VALU outer product, NO atomics) ----------------
// All indices here are STORAGE (perm'd) indices; reduce un-permutes f.

__global__ __launch_bounds__(256, 4)
void kvsum_kernel(const bf16_t* __restrict__ phik, const bf16_t* __restrict__ vb,
                  float* __restrict__ P, float* __restrict__ Zp)
{
  __shared__ bf16_t kls[64 * 128];
  __shared__ bf16_t vls[64 * 128];
  const int h = blockIdx.y;
  const int c = blockIdx.x;
  const int n0 = c * 256;
  const int tid = threadIdx.x;
  const int lane = tid & 63, wave = tid >> 6;
  const int cb = wave * 256;
  const int ek0 = (tid >> 4) * 8, ev0 = (tid & 15) * 8;
  float acc[8][8] = {};
  float zacc[8] = {};

  for (int nt = 0; nt < 4; ++nt) {
    __syncthreads();
#pragma unroll
    for (int it = 0; it < 4; ++it) {
      int ch = cb + it * 64 + lane;          // 1024 chunks of 16B per matrix
      int r = ch >> 4, c16 = ch & 15;
      const size_t gsrc = (size_t)(n0 + nt * 64 + r) * 1024 + h * 128 + c16 * 8;
      gload16(phik + gsrc, kls + (size_t)(cb + it * 64) * 8);
      gload16(vb   + gsrc, vls + (size_t)(cb + it * 64) * 8);
    }
    __syncthreads();
#pragma unroll 2
    for (int n = 0; n < 64; n++) {
      bf16x8 a8 = *(const bf16x8*)(kls + n * 128 + ek0);
      bf16x8 b8 = *(const bf16x8*)(vls + n * 128 + ev0);
      float a[8], b[8];
#pragma unroll
      for (int i = 0; i < 8; i++) { a[i] = (float)a8[i]; b[i] = (float)b8[i]; }
      if ((tid & 15) == 0) {
#pragma unroll
        for (int i = 0; i < 8; i++) zacc[i] += a[i];
      }
#pragma unroll
      for (int i = 0; i < 8; i++)
#pragma unroll
        for (int j = 0; j < 8; j++) acc[i][j] += a[i] * b[j];
    }
  }
  float* pb = P + ((size_t)h * 64 + c) * 16384;
#pragma unroll
  for (int i = 0; i < 8; i++) {
    *(float4*)(pb + (ek0 + i) * 128 + ev0)     = *(float4*)&acc[i][0];
    *(float4*)(pb + (ek0 + i) * 128 + ev0 + 4) = *(float4*)&acc[i][4];
  }
  if ((tid & 15) == 0) {
    float* zb = Zp + ((size_t)h * 64 + c) * 128;
#pragma unroll
    for (int i = 0; i < 8; i++) zb[ek0 + i] = zacc[i];
  }
}

// Reduce 64 partials/head -> Mbt[h][f_logical][d_storage] (bf16) and z[h*128+d_storage].
__global__ void reduce_kvsum_kernel(const float* __restrict__ P, const float* __restrict__ Zp,
                                    bf16_t* __restrict__ Mbt, float* __restrict__ z)
{
  int i = blockIdx.x * 256 + threadIdx.x;    // [0, 131072)
  int h = i >> 14, ds = (i >> 7) & 127, fs = i & 127;
  const float* p = P + (size_t)h * 64 * 16384 + (size_t)ds * 128 + fs;
  float s = 0.f;
#pragma unroll 8
  for (int c = 0; c < 64; ++c) s += p[(size_t)c * 16384];
  int fl = (fs & 64) | p6i(fs & 63);         // un-permute V-side index
  Mbt[(size_t)h * 16384 + fl * 128 + ds] = (bf16_t)s;
  if (i < 1024) {
    int hh = i >> 7, dd = i & 127;
    const float* q = Zp + (size_t)hh * 64 * 128 + dd;
    float sz = 0.f;
#pragma unroll 8
    for (int c = 0; c < 64; ++c) sz += q[c * 128];
    z[i] = sz;
  }
}

// ---------------- attention num/den/t ----------------

__global__ __launch_bounds__(256, 2)
void attn_t_kernel(const bf16_t* __restrict__ phiq, const bf16_t* __restrict__ Mbt,
                   const float* __restrict__ z, bf16_t* __restrict__ tout)
{
  __shared__ bf16_t As[64 * 128];   // phiq rows (storage order)
  __shared__ bf16_t Bs[128 * 128];  // Mbt[h] : [f_logical][d_storage]
  __shared__ float  zs[128];
  __shared__ float  dens[64];
  int h = blockIdx.y, row0 = blockIdx.x * 64;
  int tid = threadIdx.x, lane = tid & 63, wave = tid >> 6;
  int wr = (wave >> 1) * 32, wc = (wave & 1) * 64;
  int l15 = lane & 15, g = lane >> 4;

#pragma unroll
  for (int it = 0; it < 4; ++it) {          // A: 64x128 = 1024 chunks
    int ch = it * 256 + tid;
    int r = ch >> 4, c8 = ch & 15;
    int cs = c8 ^ (r & 7);
    *(bf16x8*)(As + r * 128 + cs * 8) = *(const bf16x8*)(phiq + (size_t)(row0 + r) * 1024 + h * 128 + c8 * 8);
  }
#pragma unroll
  for (int it = 0; it < 8; ++it) {          // B: 128x128 = 2048 chunks
    int ch = it * 256 + tid;
    int r = ch >> 4, c8 = ch & 15;
    int cs = c8 ^ (r & 7);
    *(bf16x8*)(Bs + r * 128 + cs * 8) = *(const bf16x8*)(Mbt + (size_t)h * 16384 + ch * 8);
  }
  if (tid < 128) zs[tid] = z[h * 128 + tid];
  __syncthreads();

  f32x4 acc[2][4] = {};
#pragma unroll
  for (int ks = 0; ks < 4; ++ks) {
    bf16x8 af[2], bfr[4];
#pragma unroll
    for (int i = 0; i < 2; i++) af[i]  = ldsf128(As, wr + i * 16 + l15, 256, ks * 64 + 16 * g);
#pragma unroll
    for (int j = 0; j < 4; j++) bfr[j] = ldsf128(Bs, wc + j * 16 + l15, 256, ks * 64 + 16 * g);
#pragma unroll
    for (int i = 0; i < 2; i++)
#pragma unroll
      for (int j = 0; j < 4; j++)
        acc[i][j] = __builtin_amdgcn_mfma_f32_16x16x32_bf16(af[i], bfr[j], acc[i][j], 0, 0, 0);
  }

  if (tid < 64) {                            // den (storage-order dot, skewed, swizzle-aware)
    float s = 0.f;
    const char* p = (const char*)As + tid * 256;
    int sw = (tid & 7) << 4;
    for (int d0 = 0; d0 < 128; ++d0) {
      int d = (d0 + tid) & 127;
      bf16_t kv = *(const bf16_t*)(p + ((2 * d) ^ sw));
      s += (float)kv * zs[d];
    }
    dens[tid] = s;
  }
  __syncthreads();

#pragma unroll
  for (int i = 0; i < 2; i++) {
    int lr = wr + i * 16 + g * 4;
#pragma unroll
    for (int j = 0; j < 4; j++) {
      int col = h * 128 + wc + j * 16 + l15;  // logical head-major
      f32x4 v = acc[i][j];
#pragma unroll
      for (int rr = 0; rr < 4; rr++) {
        float den = dens[lr + rr] + 1e-6f;
        tout[(size_t)(row0 + lr + rr) * 1024 + col] = (bf16_t)(v[rr] / den);
      }
    }
  }
}

// ---------------- LayerNorms ----------------

// y = LN(unpermute(t) + x) * g + b   (y written PERM'd for FFN1's k-dim)
__global__ __launch_bounds__(256, 2)
void ln1_kernel(const bf16_t* __restrict__ t, const float* __restrict__ x,
                const float* __restrict__ gma, const float* __restrict__ bta,
                bf16_t* __restrict__ y)
{
  __shared__ float s[1024];
  __shared__ float rsum[4], rsq[4];
  int n = blockIdx.x, tid = threadIdx.x;
#pragma unroll
  for (int k = 0; k < 4; k++) {
    int p = k * 256 + tid;
    float tv = (float)t[(size_t)n * 1024 + p];
    int c = ((p & 127) << 3) | (p >> 7);     // head-major -> natural
    s[c] = tv;
  }
  __syncthreads();
  float sum = 0.f, sq = 0.f, sv[4];
#pragma unroll
  for (int k = 0; k < 4; k++) {
    int c = k * 256 + tid;
    float v = s[c] + x[(size_t)n * 1024 + c];
    sv[k] = v; sum += v; sq += v * v;
  }
#pragma unroll
  for (int o = 32; o > 0; o >>= 1) { sum += __shfl_down(sum, o); sq += __shfl_down(sq, o); }
  if ((tid & 63) == 0) { rsum[tid >> 6] = sum; rsq[tid >> 6] = sq; }
  __syncthreads();
  sum = rsum[0] + rsum[1] + rsum[2] + rsum[3];
  sq  = rsq[0] + rsq[1] + rsq[2] + rsq[3];
  float mu = sum * (1.f / 1024.f);
  float var = sq * (1.f / 1024.f) - mu * mu;
  float rs = rsqrtf(var + 1e-5f);
#pragma unroll
  for (int k = 0; k < 4; k++) {
    int c = k * 256 + tid;
    y[(size_t)n * 1024 + permc(c)] = (bf16_t)((sv[k] - mu) * rs * gma[c] + bta[c]);
  }
}

// out = LN(f + y) * g + b   (f natural; y stored PERM'd; out f32 natural)
__global__ __launch_bounds__(256, 2)
void ln2_kernel(const bf16_t* __restrict__ f, const bf16_t* __restrict__ y,
                const float* __restrict__ gma, const float* __restrict__ bta,
                float* __restrict__ out)
{
  __shared__ float rsum[4], rsq[4];
  int n = blockIdx.x, tid = threadIdx.x;
  float sum = 0.f, sq = 0.f, sv[4];
#pragma unroll
  for (int k = 0; k < 4; k++) {
    int c = k * 256 + tid;
    float v = (float)f[(size_t)n * 1024 + c] + (float)y[(size_t)n * 1024 + permc(c)];
    sv[k] = v; sum += v; sq += v * v;
  }
#pragma unroll
  for (int o = 32; o > 0; o >>= 1) { sum += __shfl_down(sum, o); sq += __shfl_down(sq, o); }
  if ((tid & 63) == 0) { rsum[tid >> 6] = sum; rsq[tid >> 6] = sq; }
  __syncthreads();
  sum = rsum[0] + rsum[1] + rsum[2] + rsum[3];
  sq  = rsq[0] + rsq[1] + rsq[2] + rsq[3];
  float mu = sum * (1.f / 1024.f);
  float var = sq * (1.f / 1024.f) - mu * mu;
  float rs = rsqrtf(var + 1e-5f);
#pragma unroll
  for (int k = 0; k < 4; k++) {
    int c = k * 256 + tid;
    out[(size_t)n * 1024 + c] = (sv[k] - mu) * rs * gma[c] + bta[c];
  }
}

// ---------------- launcher ----------------

extern "C" void kernel_launch(void* const* d_in, const int* in_sizes, int n_in,
                              void* d_out, int out_size, void* d_ws, size_t ws_size,
                              hipStream_t stream)
{
  const float* x    = (const float*)d_in[0];
  const float* Wq   = (const float*)d_in[1];
  const float* Wkv  = (const float*)d_in[2];
  const float* g1   = (const float*)d_in[3];
  const float* bt1  = (const float*)d_in[4];
  const float* W1   = (const float*)d_in[5];
  const float* b1   = (const float*)d_in[6];
  const float* W2   = (const float*)d_in[7];
  const float* b2   = (const float*)d_in[8];
  const float* g2   = (const float*)d_in[9];
  const float* bt2  = (const float*)d_in[10];
  float* out = (float*)d_out;

  char* ws = (char*)d_ws;
  size_t off = 0;
  auto alloc = [&](size_t bytes) { void* p = ws + off; off += (bytes + 255) & ~(size_t)255; return p; };

  const size_t NC2 = (size_t)NROWS * CDIM * 2;          // 33.5 MB (bf16 [N][C])
  bf16_t* xb    = (bf16_t*)alloc(NC2);                  // xb; later: kvsum partials P; later: t
  bf16_t* wqkv  = (bf16_t*)alloc((size_t)3072 * 1024 * 2);
  bf16_t* w1bt  = (bf16_t*)alloc((size_t)1024 * 1024 * 2);
  bf16_t* w2bt  = (bf16_t*)alloc((size_t)1024 * 1024 * 2);
  bf16_t* phiq  = (bf16_t*)alloc(NC2);
  bf16_t* phik  = (bf16_t*)alloc(NC2);                  // later reused as h
  bf16_t* vbuf  = (bf16_t*)alloc(NC2);                  // later reused as f
  bf16_t* ybuf  = (bf16_t*)alloc(NC2);
  float*  Zp    = (float*)alloc(262144 + 4096);         // Zp[8][64][128] + z[1024]
  float*  zbuf  = Zp + 65536;
  bf16_t* Mbt   = (bf16_t*)alloc(262144);
  float*  Pbuf  = (float*)xb;                           // alias: 8*64*16384 f32 = exactly NC2 bytes
  bf16_t* tbuf  = xb;                                   // alias (P dead after reduce)
  bf16_t* hbuf  = phik;                                 // alias (phik dead after kvsum)
  bf16_t* fbuf  = vbuf;                                 // alias (v dead after kvsum)

  cast_x_kernel<<<2048, 256, 0, stream>>>(x, xb, (long)NROWS * CDIM / 8);
  prep_w_kernel<<<dim3(16, 16, 5), 256, 0, stream>>>(Wq, Wkv, W1, W2, wqkv, w1bt, w2bt);

  gemm_bt_kernel<0><<<dim3(128, 24), 256, 0, stream>>>(xb, wqkv, nullptr, phiq, phik, vbuf,
                                                       NROWS, 3072, 1024);
  kvsum_kernel<<<dim3(64, 8), 256, 0, stream>>>(phik, vbuf, Pbuf, Zp);
  reduce_kvsum_kernel<<<512, 256, 0, stream>>>(Pbuf, Zp, Mbt, zbuf);
  attn_t_kernel<<<dim3(256, 8), 256, 0, stream>>>(phiq, Mbt, zbuf, tbuf);
  ln1_kernel<<<NROWS, 256, 0, stream>>>(tbuf, x, g1, bt1, ybuf);

  gemm_bt_kernel<1><<<dim3(128, 8), 256, 0, stream>>>(ybuf, w1bt, b1, hbuf, nullptr, nullptr,
                                                      NROWS, 1024, 1024);
  gemm_bt_kernel<2><<<dim3(128, 8), 256, 0, stream>>>(hbuf, w2bt, b2, fbuf, nullptr, nullptr,
                                                      NROWS, 1024, 1024);
  ln2_kernel<<<NROWS, 256, 0, stream>>>(fbuf, ybuf, g2, bt2, out);
}